// Round 11
// baseline (126.268 us; speedup 1.0000x reference)
//
#include <hip/hip_runtime.h>
#include <math.h>

// DeformConv2dPack on MI355X (gfx950) — v11
// B=8, C=256, H=W=64, Cout=256, K=3x3, stride=1, pad=1, dil=1
//
// v11 = v8 (proven 64.8us: schedule + XOR swizzle, VGPR=64) with BK=128
//       periods: stage TWO cc-chunks into two LDS sub-buffers, ONE
//       lds_barrier, then 32 MFMAs -> barrier count 36 -> 18, halving the
//       per-barrier latency serialization that dominates v8's wall.
//       Weight loads stay post-barrier (v8 style; cross-barrier reg prefetch
//       failed 3x: v6/v9 scratch-alias, v10 occupancy step >64 VGPR).
//       + pack_w/pack_wom fused into one launch.
//
// ws layout:
//  [0)          xt bf16 NHWC   16,777,216 B
//  [16777216)   Wpack bf16      1,179,648 B
//  [17956864)   Womp bf16         147,456 B
//  [18104320)   dy fp32         1,179,648 B
//  [19283968)   dx fp32         1,179,648 B
//  [20463616)   mask fp32       1,179,648 B   (end 21,643,264)

typedef __bf16 bf16x8 __attribute__((ext_vector_type(8)));
typedef float  f32x4  __attribute__((ext_vector_type(4)));
typedef float  f32x2  __attribute__((ext_vector_type(2)));
typedef int    i32x4  __attribute__((ext_vector_type(4)));
typedef unsigned short u16x8 __attribute__((ext_vector_type(8)));
typedef unsigned short u16x4 __attribute__((ext_vector_type(4)));

__device__ __forceinline__ unsigned short f2b(float f) {
  return __builtin_bit_cast(unsigned short, (__bf16)f);
}
__device__ __forceinline__ float blo(unsigned u) {
  return __builtin_bit_cast(float, u << 16);
}
__device__ __forceinline__ float bhi(unsigned u) {
  return __builtin_bit_cast(float, u & 0xffff0000u);
}
// LDS-only barrier: drain LDS ops, keep global loads in flight.
__device__ __forceinline__ void lds_barrier() {
  asm volatile("s_waitcnt lgkmcnt(0)" ::: "memory");
  __builtin_amdgcn_s_barrier();
}

__global__ __launch_bounds__(256) void transpose_nhwc(const float* __restrict__ x,
                                                      unsigned short* __restrict__ xt) {
  __shared__ float tile[64][65];
  const int bid = blockIdx.x;
  const int b = bid & 7, rem = bid >> 3;
  const int cc = rem & 3, hw0 = (rem >> 2) << 6;
  const int t = threadIdx.x;
  const int a = t & 63, g = t >> 6;
#pragma unroll
  for (int r = 0; r < 16; ++r) {
    int crow = (r << 2) + g;
    tile[crow][a] = x[(((b << 8) + (cc << 6) + crow) << 12) + hw0 + a];
  }
  __syncthreads();
  const int a0 = (t & 15) << 2, gg = t >> 4;
#pragma unroll
  for (int r = 0; r < 4; ++r) {
    int hwr = (r << 4) + gg;
    u16x4 v;
#pragma unroll
    for (int j = 0; j < 4; ++j) v[j] = f2b(tile[a0 + j][hwr]);
    *(u16x4*)&xt[((b << 12) + hw0 + hwr) * 256 + (cc << 6) + a0] = v;
  }
}

// Fused weight packs: blocks [0,2304) -> main weight; [2304,2592) -> offset/mask.
__global__ __launch_bounds__(256) void pack_all(const float* __restrict__ w,
                                                const float* __restrict__ wo,
                                                const float* __restrict__ wm,
                                                __bf16* __restrict__ wp,
                                                __bf16* __restrict__ womp) {
  if (blockIdx.x < 2304) {
    int idx = blockIdx.x * 256 + threadIdx.x;
    int o = idx / 2304, rem = idx - o * 2304;
    int c = rem / 9, k = rem - c * 9;
    wp[(((k << 5) + (c >> 3)) * 256 + o) * 8 + (c & 7)] = (__bf16)w[idx];
  } else {
    int idx = (blockIdx.x - 2304) * 256 + threadIdx.x;
    if (idx >= 32 * 256 * 9) return;
    int r = idx / 2304, rem = idx - r * 2304;
    int c = rem / 9, k = rem - c * 9;
    float v = 0.f;
    if (r < 18) v = wo[((r << 8) + c) * 9 + k];
    else if (r < 27) v = wm[(((r - 18) << 8) + c) * 9 + k];
    womp[(((k << 5) + (c >> 3)) * 32 + r) * 8 + (c & 7)] = (__bf16)v;
  }
}

// K1: offset/mask conv. grid = 512 (bi = bid&7 XCD-swizzled, h = bid>>3), 256 thr.
// S layout: [buf][row*64 + ((g16 ^ (row&7))<<3)] shorts (16B-granule XOR swizzle).
__global__ __launch_bounds__(256) void offset_conv(
    const unsigned short* __restrict__ xt, const __bf16* __restrict__ wp,
    const float* __restrict__ b_off, const float* __restrict__ b_msk,
    float* __restrict__ dyp, float* __restrict__ dxp, float* __restrict__ mkp) {
  const int bi = blockIdx.x & 7, h = blockIdx.x >> 3;
  const int t = threadIdx.x, lane = t & 63, nw = t >> 6;
  const int l16 = lane & 15, lh = lane >> 4;
  __shared__ __align__(16) unsigned short S[2][64 * 64];
  f32x4 acc[2] = {};
  const int sp = t >> 2, sc0 = (t & 3) << 4;
  const int g0 = (t & 3) << 1;
  const int w0 = (sp << 6) + (((g0 ^ (sp & 7)) & 7) << 3);
  const int w1 = (sp << 6) + ((((g0 + 1) ^ (sp & 7)) & 7) << 3);
  const long xb = (long)bi << 20;

  auto LOAD = [&](int it, u16x8* r) {
    const int k = it >> 2, cc = it & 3;
    const int hh = h + k / 3 - 1;
    const int ww = sp + k % 3 - 1;
    const bool valid = (hh >= 0) & (hh < 64) & (ww >= 0) & (ww < 64);
    if (valid) {
      const unsigned short* src = xt + xb + (((hh << 6) + ww) << 8) + (cc << 6) + sc0;
      r[0] = *(const u16x8*)src;
      r[1] = *(const u16x8*)(src + 8);
    } else {
      r[0] = u16x8{}; r[1] = u16x8{};
    }
  };

  auto STEP = [&](int it, const u16x8* r, int buf) {
    unsigned short* Sb = S[buf];
    *(u16x8*)&Sb[w0] = r[0];
    *(u16x8*)&Sb[w1] = r[1];
    lds_barrier();
    const int k = it >> 2, cc = it & 3;
#pragma unroll
    for (int kk = 0; kk < 2; ++kk) {
      const int prow = (nw << 4) + l16;
      const int gi = (kk << 2) | lh;
      bf16x8 bfrag = *(const bf16x8*)&Sb[(prow << 6) + (((gi ^ (prow & 7)) & 7) << 3)];
#pragma unroll
      for (int mf = 0; mf < 2; ++mf) {
        const __bf16* ap = wp + ((((k << 5) + (cc << 3) + (kk << 2) + lh) << 5) + (mf << 4) + l16) * 8;
        bf16x8 af = *(const bf16x8*)ap;
        acc[mf] = __builtin_amdgcn_mfma_f32_16x16x32_bf16(af, bfrag, acc[mf], 0, 0, 0);
      }
    }
  };

  u16x8 rA[2], rB[2];
  LOAD(0, rA);
  for (int it = 0; it < 36; it += 2) {
    LOAD(it + 1, rB);
    STEP(it, rA, 0);
    if (it + 2 < 36) LOAD(it + 2, rA);
    STEP(it + 1, rB, 1);
  }

  const int p = (nw << 4) + l16;
  const int hw = (h << 6) + p;
#pragma unroll
  for (int mf = 0; mf < 2; ++mf) {
#pragma unroll
    for (int r = 0; r < 4; ++r) {
      int row = (mf << 4) + (lh << 2) + r;
      float v = acc[mf][r];
      if (row < 18) {
        v += b_off[row];
        float* dst = (row & 1) ? dxp : dyp;
        dst[(((bi * 9) + (row >> 1)) << 12) + hw] = v;
      } else if (row < 27) {
        int km = row - 18;
        v += b_msk[km];
        mkp[(((bi * 9) + km) << 12) + hw] = 1.f / (1.f + expf(-v));
      }
    }
  }
}

// K2: fused deformable-sample + GEMM. grid = 512 (bi = bid&7, h = bid>>3),
// 512 threads = 8 waves; wave wv owns out rows [wv*32, wv*32+32). Tile 256out x 64px.
// BK=128 periods: two cc-chunks staged into S[buf][0/1], ONE barrier, 32 MFMAs.
// S layout: [buf][half][row*64 + ((g16 ^ (row&7))<<3)] shorts.
__global__ __launch_bounds__(512, 2) void deform_gemm(
    const unsigned short* __restrict__ xt, const __bf16* __restrict__ wp,
    const float* __restrict__ dyp, const float* __restrict__ dxp,
    const float* __restrict__ mkp, const float* __restrict__ bias,
    float* __restrict__ out) {
  const int bi = blockIdx.x & 7, h = blockIdx.x >> 3;
  const int t = threadIdx.x, lane = t & 63, wv = t >> 6;
  const int l16 = lane & 15, lh = lane >> 4;
  __shared__ __align__(16) unsigned short S[2][2][64 * 64];  // 32 KB, swizzled
  __shared__ __align__(16) float samp[9][64][8];             // 18 KB

  // Precompute per-(tap,px) interp weights + clamped corner offsets (once).
  for (int i = t; i < 576; i += 512) {
    int k = i >> 6, p = i & 63;
    int idx = (((bi * 9) + k) << 12) + (h << 6) + p;
    float dy = dyp[idx], dx = dxp[idx], mk = mkp[idx];
    float ys = (float)(h + k / 3 - 1) + dy;
    float xs = (float)(p + k % 3 - 1) + dx;
    float y0f = floorf(ys), x0f = floorf(xs);
    int iy0 = (int)y0f, ix0 = (int)x0f;
    float wy1 = ys - y0f, wx1 = xs - x0f;
    float wy0 = 1.f - wy1, wx0 = 1.f - wx1;
    float w00 = wy0 * wx0 * mk, w01 = wy0 * wx1 * mk;
    float w10 = wy1 * wx0 * mk, w11 = wy1 * wx1 * mk;
    if (iy0 < 0 || iy0 > 63) { w00 = 0.f; w01 = 0.f; }
    if (iy0 < -1 || iy0 > 62) { w10 = 0.f; w11 = 0.f; }
    if (ix0 < 0 || ix0 > 63) { w00 = 0.f; w10 = 0.f; }
    if (ix0 < -1 || ix0 > 62) { w01 = 0.f; w11 = 0.f; }
    const int cy0 = min(max(iy0, 0), 63), cy1 = min(max(iy0 + 1, 0), 63);
    const int cx0 = min(max(ix0, 0), 63), cx1 = min(max(ix0 + 1, 0), 63);
    samp[k][p][0] = w00; samp[k][p][1] = w01;
    samp[k][p][2] = w10; samp[k][p][3] = w11;
    samp[k][p][4] = __builtin_bit_cast(float, (((cy0 << 6) + cx0) << 8));
    samp[k][p][5] = __builtin_bit_cast(float, (((cy0 << 6) + cx1) << 8));
    samp[k][p][6] = __builtin_bit_cast(float, (((cy1 << 6) + cx0) << 8));
    samp[k][p][7] = __builtin_bit_cast(float, (((cy1 << 6) + cx1) << 8));
  }
  __syncthreads();

  f32x4 acc[2][4] = {};
  const int sp = t >> 3;                  // staging pixel row, 8 thr/px
  const int sc0 = (t & 7) << 3;           // 8 ch each (granule g = t&7)
  const int wofs = (sp << 6) + ((((t & 7) ^ (sp & 7)) & 7) << 3);  // swizzled
  const unsigned short* xtb = xt + ((long)bi << 20);

  auto GATHER = [&](int it, u16x8* r, f32x4& w4) {
    const int k = it >> 2, cc = it & 3;
    w4 = *(const f32x4*)&samp[k][sp][0];
    i32x4 o4 = __builtin_bit_cast(i32x4, *(const f32x4*)&samp[k][sp][4]);
    const int c0 = (cc << 6) + sc0;
    r[0] = *(const u16x8*)(xtb + o4.x + c0);
    r[1] = *(const u16x8*)(xtb + o4.y + c0);
    r[2] = *(const u16x8*)(xtb + o4.z + c0);
    r[3] = *(const u16x8*)(xtb + o4.w + c0);
  };

  // Interp 8 channels from 4 corner regs, write to LDS sub-buffer (read-only r).
  auto INTERP_WRITE = [&](const u16x8* r, const f32x4& w4, unsigned short* dst) {
    u16x8 sv;
    const unsigned* u0 = (const unsigned*)&r[0];
    const unsigned* u1 = (const unsigned*)&r[1];
    const unsigned* u2 = (const unsigned*)&r[2];
    const unsigned* u3 = (const unsigned*)&r[3];
#pragma unroll
    for (int j = 0; j < 4; ++j) {
      f32x2 a{blo(u0[j]), bhi(u0[j])};
      f32x2 b{blo(u1[j]), bhi(u1[j])};
      f32x2 c{blo(u2[j]), bhi(u2[j])};
      f32x2 d{blo(u3[j]), bhi(u3[j])};
      f32x2 s = a * w4.x;
      s += b * w4.y;
      s += c * w4.z;
      s += d * w4.w;
      sv[2 * j]     = f2b(s.x);
      sv[2 * j + 1] = f2b(s.y);
    }
    *(u16x8*)dst = sv;
  };

  // One period: stage cc-chunks it, it+1 into S[buf][0/1]; 1 barrier; 32 MFMAs.
  auto PERIOD = [&](int it, const u16x8* r, const f32x4& w4a, const f32x4& w4b, int buf) {
    INTERP_WRITE(r,     w4a, &S[buf][0][wofs]);
    INTERP_WRITE(r + 4, w4b, &S[buf][1][wofs]);
    lds_barrier();
#pragma unroll
    for (int half = 0; half < 2; ++half) {
      const int itc = it + half;
      const int k = itc >> 2, cc = itc & 3;
#pragma unroll
      for (int kk = 0; kk < 2; ++kk) {
        bf16x8 bfr[4];
#pragma unroll
        for (int nf = 0; nf < 4; ++nf) {
          const int prow = (nf << 4) + l16;
          const int gi = (kk << 2) | lh;
          bfr[nf] = *(const bf16x8*)&S[buf][half][(prow << 6) + (((gi ^ (prow & 7)) & 7) << 3)];
        }
#pragma unroll
        for (int mf = 0; mf < 2; ++mf) {
          const int orow = (wv << 5) + (mf << 4) + l16;
          const __bf16* ap = wp + ((((k << 5) + (cc << 3) + (kk << 2) + lh) << 8) + orow) * 8;
          bf16x8 af = *(const bf16x8*)ap;
#pragma unroll
          for (int nf = 0; nf < 4; ++nf)
            acc[mf][nf] = __builtin_amdgcn_mfma_f32_16x16x32_bf16(af, bfr[nf], acc[mf][nf], 0, 0, 0);
        }
      }
    }
  };

  u16x8 rA[8], rB[8];
  f32x4 wA0, wA1, wB0, wB1;
  GATHER(0, rA, wA0);
  GATHER(1, rA + 4, wA1);
  for (int it = 0; it < 36; it += 4) {
    GATHER(it + 2, rB, wB0);
    GATHER(it + 3, rB + 4, wB1);
    PERIOD(it, rA, wA0, wA1, 0);
    if (it + 4 < 36) {
      GATHER(it + 4, rA, wA0);
      GATHER(it + 5, rA + 4, wA1);
    }
    PERIOD(it + 2, rB, wB0, wB1, 1);
  }

#pragma unroll
  for (int mf = 0; mf < 2; ++mf) {
    const int o = (wv << 5) + (mf << 4) + (lh << 2);
    f32x4 bv = *(const f32x4*)(bias + o);
#pragma unroll
    for (int nf = 0; nf < 4; ++nf) {
      const int p = (nf << 4) + l16;
      const int hw = (h << 6) + p;
#pragma unroll
      for (int r = 0; r < 4; ++r)
        out[(((bi << 8) + o + r) << 12) + hw] = acc[mf][nf][r] + bv[r];
    }
  }
}

extern "C" void kernel_launch(void* const* d_in, const int* in_sizes, int n_in,
                              void* d_out, int out_size, void* d_ws, size_t ws_size,
                              hipStream_t stream) {
  (void)in_sizes; (void)n_in; (void)out_size; (void)ws_size;
  const float* x        = (const float*)d_in[0];
  const float* w_offset = (const float*)d_in[1];
  const float* b_offset = (const float*)d_in[2];
  const float* w_mask   = (const float*)d_in[3];
  const float* b_mask   = (const float*)d_in[4];
  const float* weight   = (const float*)d_in[5];
  const float* bias     = (const float*)d_in[6];
  float* out = (float*)d_out;

  char* ws = (char*)d_ws;
  unsigned short* xt = (unsigned short*)(ws);
  __bf16* Wpack  = (__bf16*)(ws + 16777216);
  __bf16* Womp   = (__bf16*)(ws + 17956864);
  float*  dyp    = (float*)(ws + 18104320);
  float*  dxp    = (float*)(ws + 19283968);
  float*  mkp    = (float*)(ws + 20463616);

  transpose_nhwc<<<2048, 256, 0, stream>>>(x, xt);
  pack_all<<<2592, 256, 0, stream>>>(weight, w_offset, w_mask, Wpack, Womp);
  offset_conv<<<512, 256, 0, stream>>>(xt, Womp, b_offset, b_mask, dyp, dxp, mkp);
  deform_gemm<<<512, 512, 0, stream>>>(xt, Wpack, dyp, dxp, mkp, bias, out);
}

// Round 13
// 103.887 us; speedup vs baseline: 1.2154x; 1.2154x over previous
//
#include <hip/hip_runtime.h>
#include <math.h>

// DeformConv2dPack on MI355X (gfx950) — v13
// B=8, C=256, H=W=64, Cout=256, K=3x3, stride=1, pad=1, dil=1
//
// v13 = v8 (proven fastest: 64.8us deform_gemm / 106.3us total) with the
//       barrier race class removed: __syncthreads() everywhere in the main
//       loops. v12's revalidation failure was a timing-dependent race — the
//       hand-rolled {s_waitcnt lgkmcnt(0); s_barrier} has no post-barrier
//       memory fence, so ds_reads can be hoisted above s_barrier (s_barrier
//       is not an IR-level memory fence; cf. guide rule #18). R5 measured
//       lds_barrier vs __syncthreads as perf-NEUTRAL, so this costs nothing.
//       Keeps: v5 schedule, XOR bank swizzle (4.79M->74K), 64px tiles,
//       grid 512 XCD-swizzled, pack fusion (v11-validated).
//
// ws layout:
//  [0)          xt bf16 NHWC   16,777,216 B
//  [16777216)   Wpack bf16      1,179,648 B
//  [17956864)   Womp bf16         147,456 B
//  [18104320)   dy fp32         1,179,648 B
//  [19283968)   dx fp32         1,179,648 B
//  [20463616)   mask fp32       1,179,648 B   (end 21,643,264)

typedef __bf16 bf16x8 __attribute__((ext_vector_type(8)));
typedef float  f32x4  __attribute__((ext_vector_type(4)));
typedef float  f32x2  __attribute__((ext_vector_type(2)));
typedef int    i32x4  __attribute__((ext_vector_type(4)));
typedef unsigned short u16x8 __attribute__((ext_vector_type(8)));
typedef unsigned short u16x4 __attribute__((ext_vector_type(4)));

__device__ __forceinline__ unsigned short f2b(float f) {
  return __builtin_bit_cast(unsigned short, (__bf16)f);
}
__device__ __forceinline__ float blo(unsigned u) {
  return __builtin_bit_cast(float, u << 16);
}
__device__ __forceinline__ float bhi(unsigned u) {
  return __builtin_bit_cast(float, u & 0xffff0000u);
}

__global__ __launch_bounds__(256) void transpose_nhwc(const float* __restrict__ x,
                                                      unsigned short* __restrict__ xt) {
  __shared__ float tile[64][65];
  const int bid = blockIdx.x;
  const int b = bid & 7, rem = bid >> 3;
  const int cc = rem & 3, hw0 = (rem >> 2) << 6;
  const int t = threadIdx.x;
  const int a = t & 63, g = t >> 6;
#pragma unroll
  for (int r = 0; r < 16; ++r) {
    int crow = (r << 2) + g;
    tile[crow][a] = x[(((b << 8) + (cc << 6) + crow) << 12) + hw0 + a];
  }
  __syncthreads();
  const int a0 = (t & 15) << 2, gg = t >> 4;
#pragma unroll
  for (int r = 0; r < 4; ++r) {
    int hwr = (r << 4) + gg;
    u16x4 v;
#pragma unroll
    for (int j = 0; j < 4; ++j) v[j] = f2b(tile[a0 + j][hwr]);
    *(u16x4*)&xt[((b << 12) + hw0 + hwr) * 256 + (cc << 6) + a0] = v;
  }
}

// Fused weight packs: blocks [0,2304) -> main weight; [2304,2592) -> offset/mask.
__global__ __launch_bounds__(256) void pack_all(const float* __restrict__ w,
                                                const float* __restrict__ wo,
                                                const float* __restrict__ wm,
                                                __bf16* __restrict__ wp,
                                                __bf16* __restrict__ womp) {
  if (blockIdx.x < 2304) {
    int idx = blockIdx.x * 256 + threadIdx.x;
    int o = idx / 2304, rem = idx - o * 2304;
    int c = rem / 9, k = rem - c * 9;
    wp[(((k << 5) + (c >> 3)) * 256 + o) * 8 + (c & 7)] = (__bf16)w[idx];
  } else {
    int idx = (blockIdx.x - 2304) * 256 + threadIdx.x;
    if (idx >= 32 * 256 * 9) return;
    int r = idx / 2304, rem = idx - r * 2304;
    int c = rem / 9, k = rem - c * 9;
    float v = 0.f;
    if (r < 18) v = wo[((r << 8) + c) * 9 + k];
    else if (r < 27) v = wm[(((r - 18) << 8) + c) * 9 + k];
    womp[(((k << 5) + (c >> 3)) * 32 + r) * 8 + (c & 7)] = (__bf16)v;
  }
}

// K1: offset/mask conv. grid = 512 (bi = bid&7 XCD-swizzled, h = bid>>3), 256 thr.
// S layout: [buf][row*64 + ((g16 ^ (row&7))<<3)] shorts (16B-granule XOR swizzle).
__global__ __launch_bounds__(256) void offset_conv(
    const unsigned short* __restrict__ xt, const __bf16* __restrict__ wp,
    const float* __restrict__ b_off, const float* __restrict__ b_msk,
    float* __restrict__ dyp, float* __restrict__ dxp, float* __restrict__ mkp) {
  const int bi = blockIdx.x & 7, h = blockIdx.x >> 3;
  const int t = threadIdx.x, lane = t & 63, nw = t >> 6;
  const int l16 = lane & 15, lh = lane >> 4;
  __shared__ __align__(16) unsigned short S[2][64 * 64];
  f32x4 acc[2] = {};
  const int sp = t >> 2, sc0 = (t & 3) << 4;
  const int g0 = (t & 3) << 1;
  const int w0 = (sp << 6) + (((g0 ^ (sp & 7)) & 7) << 3);
  const int w1 = (sp << 6) + ((((g0 + 1) ^ (sp & 7)) & 7) << 3);
  const long xb = (long)bi << 20;

  auto LOAD = [&](int it, u16x8* r) {
    const int k = it >> 2, cc = it & 3;
    const int hh = h + k / 3 - 1;
    const int ww = sp + k % 3 - 1;
    const bool valid = (hh >= 0) & (hh < 64) & (ww >= 0) & (ww < 64);
    if (valid) {
      const unsigned short* src = xt + xb + (((hh << 6) + ww) << 8) + (cc << 6) + sc0;
      r[0] = *(const u16x8*)src;
      r[1] = *(const u16x8*)(src + 8);
    } else {
      r[0] = u16x8{}; r[1] = u16x8{};
    }
  };

  auto STEP = [&](int it, const u16x8* r, int buf) {
    unsigned short* Sb = S[buf];
    *(u16x8*)&Sb[w0] = r[0];
    *(u16x8*)&Sb[w1] = r[1];
    __syncthreads();
    const int k = it >> 2, cc = it & 3;
#pragma unroll
    for (int kk = 0; kk < 2; ++kk) {
      const int prow = (nw << 4) + l16;
      const int gi = (kk << 2) | lh;
      bf16x8 bfrag = *(const bf16x8*)&Sb[(prow << 6) + (((gi ^ (prow & 7)) & 7) << 3)];
#pragma unroll
      for (int mf = 0; mf < 2; ++mf) {
        const __bf16* ap = wp + ((((k << 5) + (cc << 3) + (kk << 2) + lh) << 5) + (mf << 4) + l16) * 8;
        bf16x8 af = *(const bf16x8*)ap;
        acc[mf] = __builtin_amdgcn_mfma_f32_16x16x32_bf16(af, bfrag, acc[mf], 0, 0, 0);
      }
    }
  };

  u16x8 rA[2], rB[2];
  LOAD(0, rA);
  for (int it = 0; it < 36; it += 2) {
    LOAD(it + 1, rB);
    STEP(it, rA, 0);
    if (it + 2 < 36) LOAD(it + 2, rA);
    STEP(it + 1, rB, 1);
  }

  const int p = (nw << 4) + l16;
  const int hw = (h << 6) + p;
#pragma unroll
  for (int mf = 0; mf < 2; ++mf) {
#pragma unroll
    for (int r = 0; r < 4; ++r) {
      int row = (mf << 4) + (lh << 2) + r;
      float v = acc[mf][r];
      if (row < 18) {
        v += b_off[row];
        float* dst = (row & 1) ? dxp : dyp;
        dst[(((bi * 9) + (row >> 1)) << 12) + hw] = v;
      } else if (row < 27) {
        int km = row - 18;
        v += b_msk[km];
        mkp[(((bi * 9) + km) << 12) + hw] = 1.f / (1.f + expf(-v));
      }
    }
  }
}

// K2: fused deformable-sample + GEMM. grid = 512 (bi = bid&7, h = bid>>3),
// 512 threads = 8 waves; wave wv owns out rows [wv*32, wv*32+32). Tile 256out x 64px.
// S layout: [buf][row*64 + ((g16 ^ (row&7))<<3)] shorts (16B-granule XOR swizzle).
__global__ __launch_bounds__(512, 2) void deform_gemm(
    const unsigned short* __restrict__ xt, const __bf16* __restrict__ wp,
    const float* __restrict__ dyp, const float* __restrict__ dxp,
    const float* __restrict__ mkp, const float* __restrict__ bias,
    float* __restrict__ out) {
  const int bi = blockIdx.x & 7, h = blockIdx.x >> 3;
  const int t = threadIdx.x, lane = t & 63, wv = t >> 6;
  const int l16 = lane & 15, lh = lane >> 4;
  __shared__ __align__(16) unsigned short S[2][64 * 64];  // 16 KB, swizzled
  __shared__ __align__(16) float samp[9][64][8];          // 18 KB

  // Precompute per-(tap,px) interp weights + clamped corner offsets (once).
  for (int i = t; i < 576; i += 512) {
    int k = i >> 6, p = i & 63;
    int idx = (((bi * 9) + k) << 12) + (h << 6) + p;
    float dy = dyp[idx], dx = dxp[idx], mk = mkp[idx];
    float ys = (float)(h + k / 3 - 1) + dy;
    float xs = (float)(p + k % 3 - 1) + dx;
    float y0f = floorf(ys), x0f = floorf(xs);
    int iy0 = (int)y0f, ix0 = (int)x0f;
    float wy1 = ys - y0f, wx1 = xs - x0f;
    float wy0 = 1.f - wy1, wx0 = 1.f - wx1;
    float w00 = wy0 * wx0 * mk, w01 = wy0 * wx1 * mk;
    float w10 = wy1 * wx0 * mk, w11 = wy1 * wx1 * mk;
    if (iy0 < 0 || iy0 > 63) { w00 = 0.f; w01 = 0.f; }
    if (iy0 < -1 || iy0 > 62) { w10 = 0.f; w11 = 0.f; }
    if (ix0 < 0 || ix0 > 63) { w00 = 0.f; w10 = 0.f; }
    if (ix0 < -1 || ix0 > 62) { w01 = 0.f; w11 = 0.f; }
    const int cy0 = min(max(iy0, 0), 63), cy1 = min(max(iy0 + 1, 0), 63);
    const int cx0 = min(max(ix0, 0), 63), cx1 = min(max(ix0 + 1, 0), 63);
    samp[k][p][0] = w00; samp[k][p][1] = w01;
    samp[k][p][2] = w10; samp[k][p][3] = w11;
    samp[k][p][4] = __builtin_bit_cast(float, (((cy0 << 6) + cx0) << 8));
    samp[k][p][5] = __builtin_bit_cast(float, (((cy0 << 6) + cx1) << 8));
    samp[k][p][6] = __builtin_bit_cast(float, (((cy1 << 6) + cx0) << 8));
    samp[k][p][7] = __builtin_bit_cast(float, (((cy1 << 6) + cx1) << 8));
  }
  __syncthreads();

  f32x4 acc[2][4] = {};
  const int sp = t >> 3;                  // staging pixel row, 8 thr/px
  const int sc0 = (t & 7) << 3;           // 8 ch each (granule g = t&7)
  const int wofs = (sp << 6) + ((((t & 7) ^ (sp & 7)) & 7) << 3);  // swizzled
  const unsigned short* xtb = xt + ((long)bi << 20);

  auto GATHER = [&](int it, u16x8* r, f32x4& w4) {
    const int k = it >> 2, cc = it & 3;
    w4 = *(const f32x4*)&samp[k][sp][0];
    i32x4 o4 = __builtin_bit_cast(i32x4, *(const f32x4*)&samp[k][sp][4]);
    const int c0 = (cc << 6) + sc0;
    r[0] = *(const u16x8*)(xtb + o4.x + c0);
    r[1] = *(const u16x8*)(xtb + o4.y + c0);
    r[2] = *(const u16x8*)(xtb + o4.z + c0);
    r[3] = *(const u16x8*)(xtb + o4.w + c0);
  };

  auto STEP = [&](int it, const u16x8* r, const f32x4& w4, int buf) {
    u16x8 sv;
    const unsigned* u0 = (const unsigned*)&r[0];
    const unsigned* u1 = (const unsigned*)&r[1];
    const unsigned* u2 = (const unsigned*)&r[2];
    const unsigned* u3 = (const unsigned*)&r[3];
#pragma unroll
    for (int j = 0; j < 4; ++j) {
      f32x2 a{blo(u0[j]), bhi(u0[j])};
      f32x2 b{blo(u1[j]), bhi(u1[j])};
      f32x2 c{blo(u2[j]), bhi(u2[j])};
      f32x2 d{blo(u3[j]), bhi(u3[j])};
      f32x2 s = a * w4.x;
      s += b * w4.y;
      s += c * w4.z;
      s += d * w4.w;
      sv[2 * j]     = f2b(s.x);
      sv[2 * j + 1] = f2b(s.y);
    }
    *(u16x8*)&S[buf][wofs] = sv;
    __syncthreads();
    const int k = it >> 2, cc = it & 3;
#pragma unroll
    for (int kk = 0; kk < 2; ++kk) {
      bf16x8 bfr[4];
#pragma unroll
      for (int nf = 0; nf < 4; ++nf) {
        const int prow = (nf << 4) + l16;
        const int gi = (kk << 2) | lh;
        bfr[nf] = *(const bf16x8*)&S[buf][(prow << 6) + (((gi ^ (prow & 7)) & 7) << 3)];
      }
#pragma unroll
      for (int mf = 0; mf < 2; ++mf) {
        const int orow = (wv << 5) + (mf << 4) + l16;
        const __bf16* ap = wp + ((((k << 5) + (cc << 3) + (kk << 2) + lh) << 8) + orow) * 8;
        bf16x8 af = *(const bf16x8*)ap;
#pragma unroll
        for (int nf = 0; nf < 4; ++nf)
          acc[mf][nf] = __builtin_amdgcn_mfma_f32_16x16x32_bf16(af, bfr[nf], acc[mf][nf], 0, 0, 0);
      }
    }
  };

  u16x8 rA[4], rB[4];
  f32x4 wA, wB;
  GATHER(0, rA, wA);
  for (int it = 0; it < 36; it += 2) {
    GATHER(it + 1, rB, wB);
    STEP(it, rA, wA, 0);
    if (it + 2 < 36) GATHER(it + 2, rA, wA);
    STEP(it + 1, rB, wB, 1);
  }

#pragma unroll
  for (int mf = 0; mf < 2; ++mf) {
    const int o = (wv << 5) + (mf << 4) + (lh << 2);
    f32x4 bv = *(const f32x4*)(bias + o);
#pragma unroll
    for (int nf = 0; nf < 4; ++nf) {
      const int p = (nf << 4) + l16;
      const int hw = (h << 6) + p;
#pragma unroll
      for (int r = 0; r < 4; ++r)
        out[(((bi << 8) + o + r) << 12) + hw] = acc[mf][nf][r] + bv[r];
    }
  }
}

extern "C" void kernel_launch(void* const* d_in, const int* in_sizes, int n_in,
                              void* d_out, int out_size, void* d_ws, size_t ws_size,
                              hipStream_t stream) {
  (void)in_sizes; (void)n_in; (void)out_size; (void)ws_size;
  const float* x        = (const float*)d_in[0];
  const float* w_offset = (const float*)d_in[1];
  const float* b_offset = (const float*)d_in[2];
  const float* w_mask   = (const float*)d_in[3];
  const float* b_mask   = (const float*)d_in[4];
  const float* weight   = (const float*)d_in[5];
  const float* bias     = (const float*)d_in[6];
  float* out = (float*)d_out;

  char* ws = (char*)d_ws;
  unsigned short* xt = (unsigned short*)(ws);
  __bf16* Wpack  = (__bf16*)(ws + 16777216);
  __bf16* Womp   = (__bf16*)(ws + 17956864);
  float*  dyp    = (float*)(ws + 18104320);
  float*  dxp    = (float*)(ws + 19283968);
  float*  mkp    = (float*)(ws + 20463616);

  transpose_nhwc<<<2048, 256, 0, stream>>>(x, xt);
  pack_all<<<2592, 256, 0, stream>>>(weight, w_offset, w_mask, Wpack, Womp);
  offset_conv<<<512, 256, 0, stream>>>(xt, Womp, b_offset, b_mask, dyp, dxp, mkp);
  deform_gemm<<<512, 512, 0, stream>>>(xt, Wpack, dyp, dxp, mkp, bias, out);
}

// Round 14
// 92.000 us; speedup vs baseline: 1.3725x; 1.1292x over previous
//
#include <hip/hip_runtime.h>
#include <math.h>

// DeformConv2dPack on MI355X (gfx950) — v14
// B=8, C=256, H=W=64, Cout=256, K=3x3, stride=1, pad=1, dil=1
//
// v14 = v13 (proven: 64.5us deform_gemm, race-free __syncthreads) with:
//  - offset_conv FUSED into deform_gemm's prologue: each block (bi,h) computes
//    its own 27x64 offset/mask GEMM (same staging+swizzle+MFMA pattern, 8
//    waves = 2mf x 4nf) into LDS offm[27][64]; dy/dx/mkp global round-trip
//    removed. Prologue latency overlaps across blocks (2 blocks/CU at
//    different phases) instead of serializing at a kernel boundary.
//  - transpose_nhwc + pack_all merged into one `prep` launch.
//  Pipeline: prep -> deform_fused (2 launches).
//
// ws layout:
//  [0)          xt bf16 NHWC   16,777,216 B
//  [16777216)   Wpack bf16      1,179,648 B
//  [17956864)   Womp bf16         147,456 B   (end 18,104,320)

typedef __bf16 bf16x8 __attribute__((ext_vector_type(8)));
typedef float  f32x4  __attribute__((ext_vector_type(4)));
typedef float  f32x2  __attribute__((ext_vector_type(2)));
typedef int    i32x4  __attribute__((ext_vector_type(4)));
typedef unsigned short u16x8 __attribute__((ext_vector_type(8)));
typedef unsigned short u16x4 __attribute__((ext_vector_type(4)));

__device__ __forceinline__ unsigned short f2b(float f) {
  return __builtin_bit_cast(unsigned short, (__bf16)f);
}
__device__ __forceinline__ float blo(unsigned u) {
  return __builtin_bit_cast(float, u << 16);
}
__device__ __forceinline__ float bhi(unsigned u) {
  return __builtin_bit_cast(float, u & 0xffff0000u);
}

// prep: blocks [0,2048) transpose x NCHW->NHWC bf16; [2048,4352) pack main
// weight; [4352,4640) pack offset/mask weights.
__global__ __launch_bounds__(256) void prep(const float* __restrict__ x,
                                            unsigned short* __restrict__ xt,
                                            const float* __restrict__ w,
                                            const float* __restrict__ wo,
                                            const float* __restrict__ wm,
                                            __bf16* __restrict__ wp,
                                            __bf16* __restrict__ womp) {
  __shared__ float tile[64][65];
  const int t = threadIdx.x;
  if (blockIdx.x < 2048) {
    const int bid = blockIdx.x;
    const int b = bid & 7, rem = bid >> 3;
    const int cc = rem & 3, hw0 = (rem >> 2) << 6;
    const int a = t & 63, g = t >> 6;
#pragma unroll
    for (int r = 0; r < 16; ++r) {
      int crow = (r << 2) + g;
      tile[crow][a] = x[(((b << 8) + (cc << 6) + crow) << 12) + hw0 + a];
    }
    __syncthreads();
    const int a0 = (t & 15) << 2, gg = t >> 4;
#pragma unroll
    for (int r = 0; r < 4; ++r) {
      int hwr = (r << 4) + gg;
      u16x4 v;
#pragma unroll
      for (int j = 0; j < 4; ++j) v[j] = f2b(tile[a0 + j][hwr]);
      *(u16x4*)&xt[((b << 12) + hw0 + hwr) * 256 + (cc << 6) + a0] = v;
    }
  } else if (blockIdx.x < 4352) {
    int idx = (blockIdx.x - 2048) * 256 + t;
    int o = idx / 2304, rem = idx - o * 2304;
    int c = rem / 9, k = rem - c * 9;
    wp[(((k << 5) + (c >> 3)) * 256 + o) * 8 + (c & 7)] = (__bf16)w[idx];
  } else {
    int idx = (blockIdx.x - 4352) * 256 + t;
    if (idx >= 32 * 256 * 9) return;
    int r = idx / 2304, rem = idx - r * 2304;
    int c = rem / 9, k = rem - c * 9;
    float v = 0.f;
    if (r < 18) v = wo[((r << 8) + c) * 9 + k];
    else if (r < 27) v = wm[(((r - 18) << 8) + c) * 9 + k];
    womp[(((k << 5) + (c >> 3)) * 32 + r) * 8 + (c & 7)] = (__bf16)v;
  }
}

// deform_fused: grid = 512 (bi = bid&7 XCD, h = bid>>3), 512 threads (8 waves).
// Prologue: offset/mask conv for this row (M=32x N=64, 8 waves = 2mf x 4nf)
//           -> offm[27][64] in LDS. Then samp precompute, then main GEMM.
// S layout: [buf][row*64 + ((g16 ^ (row&7))<<3)] shorts (16B-granule XOR swizzle).
__global__ __launch_bounds__(512, 2) void deform_fused(
    const unsigned short* __restrict__ xt, const __bf16* __restrict__ wp,
    const __bf16* __restrict__ womp, const float* __restrict__ b_off,
    const float* __restrict__ b_msk, const float* __restrict__ bias,
    float* __restrict__ out) {
  const int bi = blockIdx.x & 7, h = blockIdx.x >> 3;
  const int t = threadIdx.x, lane = t & 63, wv = t >> 6;
  const int l16 = lane & 15, lh = lane >> 4;
  __shared__ __align__(16) unsigned short S[2][64 * 64];  // 16 KB, swizzled
  __shared__ __align__(16) float samp[9][64][8];          // 18 KB
  __shared__ __align__(16) float offm[27][64];            // 6.75 KB

  const int sp = t >> 3;                  // staging pixel row, 8 thr/px
  const int sc0 = (t & 7) << 3;           // 8 ch each (granule g = t&7)
  const int wofs = (sp << 6) + ((((t & 7) ^ (sp & 7)) & 7) << 3);  // swizzled
  const unsigned short* xtb = xt + ((long)bi << 20);

  // ---- Prologue: offset/mask conv (27 rows x 64 px, K=2304) ----
  {
    f32x4 oacc = {};
    const int mf = wv & 1, nf = wv >> 1;

    auto POLOAD = [&](int it, u16x8* r) {
      const int k = it >> 2, cc = it & 3;
      const int hh = h + k / 3 - 1;
      const int ww = sp + (k % 3) - 1;
      const bool valid = (hh >= 0) & (hh < 64) & (ww >= 0) & (ww < 64);
      if (valid)
        r[0] = *(const u16x8*)(xtb + (((hh << 6) + ww) << 8) + (cc << 6) + sc0);
      else
        r[0] = u16x8{};
    };

    auto POSTEP = [&](int it, const u16x8* r, int buf) {
      *(u16x8*)&S[buf][wofs] = r[0];
      __syncthreads();
      const int k = it >> 2, cc = it & 3;
#pragma unroll
      for (int kk = 0; kk < 2; ++kk) {
        const int prow = (nf << 4) + l16;
        const int gi = (kk << 2) | lh;
        bf16x8 bfrag = *(const bf16x8*)&S[buf][(prow << 6) + (((gi ^ (prow & 7)) & 7) << 3)];
        const __bf16* ap =
            womp + ((((k << 5) + (cc << 3) + (kk << 2) + lh) << 5) + (mf << 4) + l16) * 8;
        bf16x8 af = *(const bf16x8*)ap;
        oacc = __builtin_amdgcn_mfma_f32_16x16x32_bf16(af, bfrag, oacc, 0, 0, 0);
      }
    };

    u16x8 pA[1], pB[1];
    POLOAD(0, pA);
    for (int it = 0; it < 36; it += 2) {
      POLOAD(it + 1, pB);
      POSTEP(it, pA, 0);
      if (it + 2 < 36) POLOAD(it + 2, pA);
      POSTEP(it + 1, pB, 1);
    }

    const int px = (nf << 4) + l16;
#pragma unroll
    for (int r = 0; r < 4; ++r) {
      int row = (mf << 4) + (lh << 2) + r;
      if (row < 18) {
        offm[row][px] = oacc[r] + b_off[row];
      } else if (row < 27) {
        float v = oacc[r] + b_msk[row - 18];
        offm[row][px] = 1.f / (1.f + expf(-v));
      }
    }
    __syncthreads();
  }

  // ---- Precompute per-(tap,px) interp weights + clamped corner offsets ----
  for (int i = t; i < 576; i += 512) {
    int k = i >> 6, p = i & 63;
    float dy = offm[(k << 1)][p], dx = offm[(k << 1) + 1][p], mk = offm[18 + k][p];
    float ys = (float)(h + k / 3 - 1) + dy;
    float xs = (float)(p + k % 3 - 1) + dx;
    float y0f = floorf(ys), x0f = floorf(xs);
    int iy0 = (int)y0f, ix0 = (int)x0f;
    float wy1 = ys - y0f, wx1 = xs - x0f;
    float wy0 = 1.f - wy1, wx0 = 1.f - wx1;
    float w00 = wy0 * wx0 * mk, w01 = wy0 * wx1 * mk;
    float w10 = wy1 * wx0 * mk, w11 = wy1 * wx1 * mk;
    if (iy0 < 0 || iy0 > 63) { w00 = 0.f; w01 = 0.f; }
    if (iy0 < -1 || iy0 > 62) { w10 = 0.f; w11 = 0.f; }
    if (ix0 < 0 || ix0 > 63) { w00 = 0.f; w10 = 0.f; }
    if (ix0 < -1 || ix0 > 62) { w01 = 0.f; w11 = 0.f; }
    const int cy0 = min(max(iy0, 0), 63), cy1 = min(max(iy0 + 1, 0), 63);
    const int cx0 = min(max(ix0, 0), 63), cx1 = min(max(ix0 + 1, 0), 63);
    samp[k][p][0] = w00; samp[k][p][1] = w01;
    samp[k][p][2] = w10; samp[k][p][3] = w11;
    samp[k][p][4] = __builtin_bit_cast(float, (((cy0 << 6) + cx0) << 8));
    samp[k][p][5] = __builtin_bit_cast(float, (((cy0 << 6) + cx1) << 8));
    samp[k][p][6] = __builtin_bit_cast(float, (((cy1 << 6) + cx0) << 8));
    samp[k][p][7] = __builtin_bit_cast(float, (((cy1 << 6) + cx1) << 8));
  }
  __syncthreads();

  // ---- Main deformable GEMM (unchanged from v13) ----
  f32x4 acc[2][4] = {};

  auto GATHER = [&](int it, u16x8* r, f32x4& w4) {
    const int k = it >> 2, cc = it & 3;
    w4 = *(const f32x4*)&samp[k][sp][0];
    i32x4 o4 = __builtin_bit_cast(i32x4, *(const f32x4*)&samp[k][sp][4]);
    const int c0 = (cc << 6) + sc0;
    r[0] = *(const u16x8*)(xtb + o4.x + c0);
    r[1] = *(const u16x8*)(xtb + o4.y + c0);
    r[2] = *(const u16x8*)(xtb + o4.z + c0);
    r[3] = *(const u16x8*)(xtb + o4.w + c0);
  };

  auto STEP = [&](int it, const u16x8* r, const f32x4& w4, int buf) {
    u16x8 sv;
    const unsigned* u0 = (const unsigned*)&r[0];
    const unsigned* u1 = (const unsigned*)&r[1];
    const unsigned* u2 = (const unsigned*)&r[2];
    const unsigned* u3 = (const unsigned*)&r[3];
#pragma unroll
    for (int j = 0; j < 4; ++j) {
      f32x2 a{blo(u0[j]), bhi(u0[j])};
      f32x2 b{blo(u1[j]), bhi(u1[j])};
      f32x2 c{blo(u2[j]), bhi(u2[j])};
      f32x2 d{blo(u3[j]), bhi(u3[j])};
      f32x2 s = a * w4.x;
      s += b * w4.y;
      s += c * w4.z;
      s += d * w4.w;
      sv[2 * j]     = f2b(s.x);
      sv[2 * j + 1] = f2b(s.y);
    }
    *(u16x8*)&S[buf][wofs] = sv;
    __syncthreads();
    const int k = it >> 2, cc = it & 3;
#pragma unroll
    for (int kk = 0; kk < 2; ++kk) {
      bf16x8 bfr[4];
#pragma unroll
      for (int nf = 0; nf < 4; ++nf) {
        const int prow = (nf << 4) + l16;
        const int gi = (kk << 2) | lh;
        bfr[nf] = *(const bf16x8*)&S[buf][(prow << 6) + (((gi ^ (prow & 7)) & 7) << 3)];
      }
#pragma unroll
      for (int mf = 0; mf < 2; ++mf) {
        const int orow = (wv << 5) + (mf << 4) + l16;
        const __bf16* ap = wp + ((((k << 5) + (cc << 3) + (kk << 2) + lh) << 8) + orow) * 8;
        bf16x8 af = *(const bf16x8*)ap;
#pragma unroll
        for (int nf = 0; nf < 4; ++nf)
          acc[mf][nf] = __builtin_amdgcn_mfma_f32_16x16x32_bf16(af, bfr[nf], acc[mf][nf], 0, 0, 0);
      }
    }
  };

  u16x8 rA[4], rB[4];
  f32x4 wA, wB;
  GATHER(0, rA, wA);
  for (int it = 0; it < 36; it += 2) {
    GATHER(it + 1, rB, wB);
    STEP(it, rA, wA, 0);
    if (it + 2 < 36) GATHER(it + 2, rA, wA);
    STEP(it + 1, rB, wB, 1);
  }

#pragma unroll
  for (int mf = 0; mf < 2; ++mf) {
    const int o = (wv << 5) + (mf << 4) + (lh << 2);
    f32x4 bv = *(const f32x4*)(bias + o);
#pragma unroll
    for (int nf = 0; nf < 4; ++nf) {
      const int p = (nf << 4) + l16;
      const int hw = (h << 6) + p;
#pragma unroll
      for (int r = 0; r < 4; ++r)
        out[(((bi << 8) + o + r) << 12) + hw] = acc[mf][nf][r] + bv[r];
    }
  }
}

extern "C" void kernel_launch(void* const* d_in, const int* in_sizes, int n_in,
                              void* d_out, int out_size, void* d_ws, size_t ws_size,
                              hipStream_t stream) {
  (void)in_sizes; (void)n_in; (void)out_size; (void)ws_size;
  const float* x        = (const float*)d_in[0];
  const float* w_offset = (const float*)d_in[1];
  const float* b_offset = (const float*)d_in[2];
  const float* w_mask   = (const float*)d_in[3];
  const float* b_mask   = (const float*)d_in[4];
  const float* weight   = (const float*)d_in[5];
  const float* bias     = (const float*)d_in[6];
  float* out = (float*)d_out;

  char* ws = (char*)d_ws;
  unsigned short* xt = (unsigned short*)(ws);
  __bf16* Wpack  = (__bf16*)(ws + 16777216);
  __bf16* Womp   = (__bf16*)(ws + 17956864);

  prep<<<4640, 256, 0, stream>>>(x, xt, weight, w_offset, w_mask, Wpack, Womp);
  deform_fused<<<512, 512, 0, stream>>>(xt, Wpack, Womp, b_offset, b_mask, bias, out);
}